// Round 1
// baseline (389.055 us; speedup 1.0000x reference)
//
#include <hip/hip_runtime.h>
#include <hip/hip_bf16.h>

typedef __bf16 bf16x8 __attribute__((ext_vector_type(8)));
typedef float f32x4 __attribute__((ext_vector_type(4)));

#define B_  32
#define H_  128
#define W_  128
#define C_  64
#define F_  64
#define KDIM 576            // 3*3*64

// ---------------- Pass 1: pooled sums (mean * 16384) ----------------
// grid 2048 blocks x 256 thr; each block: 4096 contiguous float4 (within one b)
__global__ void pool_kernel(const float* __restrict__ x, float* __restrict__ pooled) {
    __shared__ float red[64];
    const int tid = threadIdx.x;
    if (tid < 64) red[tid] = 0.f;
    __syncthreads();
    const int b = blockIdx.x >> 6;                 // 64 blocks per sample
    const float4* x4 = reinterpret_cast<const float4*>(x) + (long)blockIdx.x * 4096;
    float4 s = {0.f, 0.f, 0.f, 0.f};
    #pragma unroll
    for (int i = 0; i < 16; ++i) {
        float4 v = x4[tid + 256 * i];
        s.x += v.x; s.y += v.y; s.z += v.z; s.w += v.w;
    }
    const int c0 = (tid & 15) * 4;                 // channel group is tid%16 (4096%16==0)
    atomicAdd(&red[c0 + 0], s.x);
    atomicAdd(&red[c0 + 1], s.y);
    atomicAdd(&red[c0 + 2], s.z);
    atomicAdd(&red[c0 + 3], s.w);
    __syncthreads();
    if (tid < 64) atomicAdd(&pooled[b * 64 + tid], red[tid]);
}

// ---------------- Pass 2: attention MLP + weight aggregation ----------------
// grid 32 blocks (one per sample) x 256 thr
__global__ void att_kernel(const float* __restrict__ pooled,
                           const float* __restrict__ Wk, const float* __restrict__ bk,
                           const float* __restrict__ w1, const float* __restrict__ b1,
                           const float* __restrict__ w2, const float* __restrict__ b2,
                           __hip_bfloat16* __restrict__ Wt, float* __restrict__ bagg) {
    const int b = blockIdx.x, tid = threadIdx.x;
    __shared__ float hsh[16], lg[4], pish[4];
    if (tid < 16) {
        float a = 0.f;
        for (int c = 0; c < 64; ++c)
            a += pooled[b * 64 + c] * (1.f / 16384.f) * w1[c * 16 + tid];
        hsh[tid] = fmaxf(a + b1[tid], 0.f);
    }
    __syncthreads();
    if (tid < 4) {
        float a = 0.f;
        for (int j = 0; j < 16; ++j) a += hsh[j] * w2[j * 4 + tid];
        lg[tid] = (a + b2[tid]) * (1.0f / 30.0f);
    }
    __syncthreads();
    if (tid == 0) {
        float m = fmaxf(fmaxf(lg[0], lg[1]), fmaxf(lg[2], lg[3]));
        float e0 = expf(lg[0] - m), e1 = expf(lg[1] - m), e2 = expf(lg[2] - m), e3 = expf(lg[3] - m);
        float inv = 1.f / (e0 + e1 + e2 + e3);
        pish[0] = e0 * inv; pish[1] = e1 * inv; pish[2] = e2 * inv; pish[3] = e3 * inv;
    }
    __syncthreads();
    const float p0 = pish[0], p1 = pish[1], p2 = pish[2], p3 = pish[3];
    if (tid < 64)
        bagg[b * 64 + tid] = p0 * bk[tid] + p1 * bk[64 + tid] + p2 * bk[128 + tid] + p3 * bk[192 + tid];
    // W_aggT[b][f][r], r = (dh*3+dw)*64 + c ; Wk flat = k*36864 + r*64 + f
    for (int idx = tid; idx < 36864; idx += 256) {
        const int f = idx / 576;
        const int r = idx - f * 576;
        const float* wp = Wk + r * 64 + f;
        float v = p0 * wp[0] + p1 * wp[36864] + p2 * wp[73728] + p3 * wp[110592];
        Wt[(long)b * 36864 + idx] = __float2bfloat16(v);
    }
}

// ---------------- Pass 3: MFMA implicit-GEMM conv ----------------
// tile: 16 rows x 32 cols per block, 4 waves (wave = 4 rows x 32 cols = 8 m-frags)
// LDS: xs [18][34][64] bf16 (78336 B, swizzled ^((col&7)<<4))
//      wl [64][576]  bf16 (73728 B at +78336, swizzled ^((f&7)<<4))
__global__ __launch_bounds__(256, 1)
void conv_kernel(const float* __restrict__ x, const __hip_bfloat16* __restrict__ Wt,
                 const float* __restrict__ bagg, float* __restrict__ out) {
    extern __shared__ char smem[];
    const int tid = threadIdx.x;
    const int bid = blockIdx.x;
    const int b  = bid >> 5;
    const int t  = bid & 31;
    const int h0 = (t >> 2) * 16;
    const int w0 = (t & 3) * 32;

    // ---- stage x tile (fp32 -> bf16), zero-padded borders ----
    const long xbase = (long)b * (H_ * W_ * C_);
    for (int g = tid; g < 18 * 34 * 8; g += 256) {      // 4896 granules of 8 ch
        const int r   = g / 272;
        const int rem = g - r * 272;
        const int col = rem >> 3;
        const int cg  = rem & 7;
        const int gh = h0 - 1 + r, gw = w0 - 1 + col;
        float4 v0 = {0.f, 0.f, 0.f, 0.f}, v1 = {0.f, 0.f, 0.f, 0.f};
        if ((unsigned)gh < 128u && (unsigned)gw < 128u) {
            const float4* src = reinterpret_cast<const float4*>(x + xbase + ((gh * 128 + gw) * 64 + cg * 8));
            v0 = src[0]; v1 = src[1];
        }
        bf16x8 o;
        o[0] = (__bf16)v0.x; o[1] = (__bf16)v0.y; o[2] = (__bf16)v0.z; o[3] = (__bf16)v0.w;
        o[4] = (__bf16)v1.x; o[5] = (__bf16)v1.y; o[6] = (__bf16)v1.z; o[7] = (__bf16)v1.w;
        int off = ((r * 34 + col) * 64 + cg * 8) * 2;
        off ^= ((col & 7) << 4);
        *reinterpret_cast<bf16x8*>(smem + off) = o;
    }
    // ---- stage W (bf16, already transposed [f][k]) ----
    const __hip_bfloat16* wsrc = Wt + (long)b * 36864;
    for (int g = tid; g < 64 * 72; g += 256) {          // 4608 granules of 8 k
        const int f  = g / 72;
        const int ks = g - f * 72;
        ulonglong2 val = *reinterpret_cast<const ulonglong2*>(wsrc + f * 576 + ks * 8);
        int off = (f * 576 + ks * 8) * 2;
        off ^= ((f & 7) << 4);
        *reinterpret_cast<ulonglong2*>(smem + 78336 + off) = val;
    }
    __syncthreads();

    const int lane = tid & 63;
    const int wid  = tid >> 6;        // 0..3 -> rows 4*wid..4*wid+3
    const int l15  = lane & 15;
    const int q    = lane >> 4;       // k-chunk / C-row-group

    f32x4 zero = {0.f, 0.f, 0.f, 0.f};
    f32x4 acc[8][4];
    #pragma unroll
    for (int mf = 0; mf < 8; ++mf)
        #pragma unroll
        for (int nf = 0; nf < 4; ++nf) acc[mf][nf] = zero;

    float bagg_v[4];
    #pragma unroll
    for (int nf = 0; nf < 4; ++nf) bagg_v[nf] = bagg[b * 64 + nf * 16 + l15];

    // ---- barrier-free K loop: everything resident in LDS ----
    #pragma unroll
    for (int s = 0; s < 18; ++s) {
        const int dhdw = s >> 1;
        const int dh = dhdw / 3;
        const int dw = dhdw - dh * 3;
        const int cb = (s & 1) * 32;
        bf16x8 bf[4];
        #pragma unroll
        for (int nf = 0; nf < 4; ++nf) {
            const int f = nf * 16 + l15;
            int off = (f * 576 + s * 32 + q * 8) * 2;
            off ^= ((f & 7) << 4);
            bf[nf] = *reinterpret_cast<const bf16x8*>(smem + 78336 + off);
        }
        #pragma unroll
        for (int mf = 0; mf < 8; ++mf) {
            const int r   = 4 * wid + (mf >> 1) + dh;
            const int col = (mf & 1) * 16 + l15 + dw;
            int off = ((r * 34 + col) * 64 + cb + q * 8) * 2;
            off ^= ((col & 7) << 4);
            const bf16x8 af = *reinterpret_cast<const bf16x8*>(smem + off);
            #pragma unroll
            for (int nf = 0; nf < 4; ++nf)
                acc[mf][nf] = __builtin_amdgcn_mfma_f32_16x16x32_bf16(af, bf[nf], acc[mf][nf], 0, 0, 0);
        }
    }

    // ---- epilogue: C row = q*4+j (pixel w), col = l15 (f) ----
    #pragma unroll
    for (int mf = 0; mf < 8; ++mf) {
        const int h = h0 + 4 * wid + (mf >> 1);
        const int wb = w0 + (mf & 1) * 16;
        #pragma unroll
        for (int nf = 0; nf < 4; ++nf) {
            const int f = nf * 16 + l15;
            #pragma unroll
            for (int j = 0; j < 4; ++j) {
                const int w = wb + q * 4 + j;
                out[(((long)b * 128 + h) * 128 + w) * 64 + f] = acc[mf][nf][j] + bagg_v[nf];
            }
        }
    }
}

extern "C" void kernel_launch(void* const* d_in, const int* in_sizes, int n_in,
                              void* d_out, int out_size, void* d_ws, size_t ws_size,
                              hipStream_t stream) {
    const float* x   = (const float*)d_in[0];
    const float* Wk  = (const float*)d_in[1];
    const float* bk  = (const float*)d_in[2];
    const float* w1  = (const float*)d_in[3];
    const float* b1  = (const float*)d_in[4];
    const float* w2  = (const float*)d_in[5];
    const float* b2  = (const float*)d_in[6];
    float* out = (float*)d_out;

    char* ws = (char*)d_ws;
    float* pooled = (float*)ws;                        // 32*64*4 = 8 KB
    float* bagg   = (float*)(ws + 8192);               // 8 KB
    __hip_bfloat16* Wt = (__hip_bfloat16*)(ws + 16384); // 32*36864*2 = 2.25 MB

    hipMemsetAsync(pooled, 0, 32 * 64 * sizeof(float), stream);
    pool_kernel<<<2048, 256, 0, stream>>>(x, pooled);
    att_kernel<<<32, 256, 0, stream>>>(pooled, Wk, bk, w1, b1, w2, b2, Wt, bagg);

    static bool attr_set = false;
    if (!attr_set) {
        hipFuncSetAttribute((const void*)conv_kernel,
                            hipFuncAttributeMaxDynamicSharedMemorySize, 152064);
        attr_set = true;
    }
    conv_kernel<<<1024, 256, 152064, stream>>>(x, Wt, bagg, out);
}

// Round 2
// 317.071 us; speedup vs baseline: 1.2270x; 1.2270x over previous
//
#include <hip/hip_runtime.h>
#include <hip/hip_bf16.h>
#include <stdint.h>

typedef __bf16 bf16x8 __attribute__((ext_vector_type(8)));
typedef float f32x4 __attribute__((ext_vector_type(4)));

#define XS_BYTES 46080   // 18 rows * 10 px * 64 ch * 4 B

__device__ __forceinline__ void load_lds16(const void* gsrc, void* ldst) {
    __builtin_amdgcn_global_load_lds(
        (const __attribute__((address_space(1))) uint32_t*)gsrc,
        (__attribute__((address_space(3))) uint32_t*)ldst, 16, 0, 0);
}

// ---------------- Pass 1: pooled sums (mean * 16384) ----------------
__global__ void pool_kernel(const float* __restrict__ x, float* __restrict__ pooled) {
    __shared__ float red[64];
    const int tid = threadIdx.x;
    if (tid < 64) red[tid] = 0.f;
    __syncthreads();
    const int b = blockIdx.x >> 6;
    const float4* x4 = reinterpret_cast<const float4*>(x) + (long)blockIdx.x * 4096;
    float4 s = {0.f, 0.f, 0.f, 0.f};
    #pragma unroll
    for (int i = 0; i < 16; ++i) {
        float4 v = x4[tid + 256 * i];
        s.x += v.x; s.y += v.y; s.z += v.z; s.w += v.w;
    }
    const int c0 = (tid & 15) * 4;
    atomicAdd(&red[c0 + 0], s.x);
    atomicAdd(&red[c0 + 1], s.y);
    atomicAdd(&red[c0 + 2], s.z);
    atomicAdd(&red[c0 + 3], s.w);
    __syncthreads();
    if (tid < 64) atomicAdd(&pooled[b * 64 + tid], red[tid]);
}

// ---------------- Pass 2: attention MLP + weight aggregation (transposed) ----
// grid (32 samples, 9 k-slabs) x 256 thr. Wt[b][f][k] bf16, k = (dh*3+dw)*64+c.
__global__ __launch_bounds__(256)
void wagg_kernel(const float* __restrict__ pooled, const float* __restrict__ Wk,
                 const float* __restrict__ bk,
                 const float* __restrict__ w1, const float* __restrict__ b1,
                 const float* __restrict__ w2, const float* __restrict__ b2,
                 __hip_bfloat16* __restrict__ Wt, float* __restrict__ bagg) {
    const int b = blockIdx.x, j = blockIdx.y, tid = threadIdx.x;
    __shared__ float accs[64][64];
    __shared__ float hsh[16], lg[4], pish[4];

    // issue coalesced Wk slab loads first (overlap with pi computation)
    const int f4 = (tid & 15) * 4;
    const int kr = tid >> 4;
    float4 v[4][4];
    #pragma unroll
    for (int pass = 0; pass < 4; ++pass) {
        const int k = j * 64 + pass * 16 + kr;
        #pragma unroll
        for (int kk = 0; kk < 4; ++kk)
            v[pass][kk] = *reinterpret_cast<const float4*>(Wk + (size_t)kk * 36864 + k * 64 + f4);
    }
    if (tid < 16) {
        float a = 0.f;
        for (int c = 0; c < 64; ++c)
            a += pooled[b * 64 + c] * (1.f / 16384.f) * w1[c * 16 + tid];
        hsh[tid] = fmaxf(a + b1[tid], 0.f);
    }
    __syncthreads();
    if (tid < 4) {
        float a = 0.f;
        for (int jj = 0; jj < 16; ++jj) a += hsh[jj] * w2[jj * 4 + tid];
        lg[tid] = (a + b2[tid]) * (1.f / 30.f);
    }
    __syncthreads();
    if (tid == 0) {
        float m = fmaxf(fmaxf(lg[0], lg[1]), fmaxf(lg[2], lg[3]));
        float e0 = expf(lg[0] - m), e1 = expf(lg[1] - m), e2 = expf(lg[2] - m), e3 = expf(lg[3] - m);
        float inv = 1.f / (e0 + e1 + e2 + e3);
        pish[0] = e0 * inv; pish[1] = e1 * inv; pish[2] = e2 * inv; pish[3] = e3 * inv;
    }
    __syncthreads();
    const float p0 = pish[0], p1 = pish[1], p2 = pish[2], p3 = pish[3];
    #pragma unroll
    for (int pass = 0; pass < 4; ++pass) {
        float4 a;
        a.x = p0*v[pass][0].x + p1*v[pass][1].x + p2*v[pass][2].x + p3*v[pass][3].x;
        a.y = p0*v[pass][0].y + p1*v[pass][1].y + p2*v[pass][2].y + p3*v[pass][3].y;
        a.z = p0*v[pass][0].z + p1*v[pass][1].z + p2*v[pass][2].z + p3*v[pass][3].z;
        a.w = p0*v[pass][0].w + p1*v[pass][1].w + p2*v[pass][2].w + p3*v[pass][3].w;
        *reinterpret_cast<float4*>(&accs[pass * 16 + kr][f4]) = a;
    }
    __syncthreads();
    const int f = tid & 63;
    const int kgo0 = (tid >> 6) * 2;
    #pragma unroll
    for (int t2 = 0; t2 < 2; ++t2) {
        const int kgo = kgo0 + t2;
        bf16x8 o;
        #pragma unroll
        for (int i = 0; i < 8; ++i) o[i] = (__bf16)accs[kgo * 8 + i][f];
        *reinterpret_cast<bf16x8*>(Wt + (size_t)b * 36864 + f * 576 + (j * 8 + kgo) * 8) = o;
    }
    if (j == 0 && tid < 64)
        bagg[b * 64 + tid] = p0*bk[tid] + p1*bk[64+tid] + p2*bk[128+tid] + p3*bk[192+tid];
}

// ---------------- Pass 3: conv, B-in-registers + async dbuf x staging -------
// 256 blocks x 256 thr (4 waves, 1 wave/SIMD, 512-VGPR budget).
// block = (sample b, row-stripe th); 16 tiles of 16x8 pixels each.
// LDS: 2 x [18 rows][10 px][64 ch] fp32, source-preswizzled ^((p&7) granule).
__global__ __launch_bounds__(256, 1)
void conv_kernel(const float* __restrict__ x, const __hip_bfloat16* __restrict__ Wt,
                 const float* __restrict__ bagg, const float* __restrict__ zeros,
                 float* __restrict__ out) {
    extern __shared__ char smem[];
    const int tid = threadIdx.x;
    const int b  = blockIdx.x >> 3;
    const int th = blockIdx.x & 7;
    const int lane = tid & 63;
    const int wv  = tid >> 6;
    const int l15 = lane & 15;
    const int q   = lane >> 4;

    // ---- B fragments (full 64x576) into registers: 288 VGPRs ----
    bf16x8 Bf[4][18];
    {
        const __hip_bfloat16* Wb = Wt + (size_t)b * 36864;
        #pragma unroll
        for (int nf = 0; nf < 4; ++nf) {
            const __hip_bfloat16* fp = Wb + (nf * 16 + l15) * 576 + q * 8;
            #pragma unroll
            for (int s = 0; s < 18; ++s)
                Bf[nf][s] = *reinterpret_cast<const bf16x8*>(fp + s * 32);
        }
    }
    float bagg_v[4];
    #pragma unroll
    for (int nf = 0; nf < 4; ++nf) bagg_v[nf] = bagg[b * 64 + nf * 16 + l15];

    const size_t xb = (size_t)b * (128 * 128 * 64);
    const int h0 = th * 16 - 1;
    const int wave_g0 = tid & 192;

    auto stage = [&](int buf, int tw) {
        const int w0 = tw * 8 - 1;
        char* bufb = smem + buf * XS_BYTES;
        #pragma unroll
        for (int i = 0; i < 12; ++i) {
            const int g = i * 256 + tid;
            if (g < 2880) {
                const int r  = g / 160;
                const int u  = g - r * 160;
                const int p  = u >> 4;
                const int cg = u & 15;
                const int gh = h0 + r, gw = w0 + p;
                const int scg = cg ^ (p & 7);        // pre-swizzled source granule
                const float* src = ((unsigned)gh < 128u && (unsigned)gw < 128u)
                    ? x + xb + (size_t)(gh * 128 + gw) * 64 + scg * 4
                    : zeros + scg * 4;
                load_lds16(src, bufb + ((i * 256 + wave_g0) << 4));
            }
        }
    };

    stage(0, 0);
    __syncthreads();                                 // drains vmcnt before barrier

    #pragma unroll 1
    for (int tw = 0; tw < 16; ++tw) {
        if (tw < 15) stage((tw + 1) & 1, tw + 1);    // async prefetch next tile
        const char* bufb = smem + (tw & 1) * XS_BYTES;

        f32x4 acc[2][4];
        #pragma unroll
        for (int mf = 0; mf < 2; ++mf)
            #pragma unroll
            for (int nf = 0; nf < 4; ++nf) acc[mf][nf] = (f32x4){0.f, 0.f, 0.f, 0.f};

        #pragma unroll
        for (int s = 0; s < 18; ++s) {
            const int tap = s >> 1;
            const int dh  = tap / 3;
            const int dw  = tap - dh * 3;
            const int cg0 = (s & 1) * 8 + q * 2;     // fp32 channel-granule base
            #pragma unroll
            for (int mf = 0; mf < 2; ++mf) {
                // pixel P = wv*32 + mf*16 + l15 -> tile row P>>3, col P&7
                const int r = wv * 4 + mf * 2 + (l15 >> 3) + dh;
                const int c = (l15 & 7) + dw;
                const int gbase = (r * 160 + c * 16 + cg0) << 4;
                const int sw = (c & 7) << 4;
                const f32x4 x0 = *reinterpret_cast<const f32x4*>(bufb + (gbase ^ sw));
                const f32x4 x1 = *reinterpret_cast<const f32x4*>(bufb + ((gbase + 16) ^ sw));
                bf16x8 af;
                af[0] = (__bf16)x0[0]; af[1] = (__bf16)x0[1];
                af[2] = (__bf16)x0[2]; af[3] = (__bf16)x0[3];
                af[4] = (__bf16)x1[0]; af[5] = (__bf16)x1[1];
                af[6] = (__bf16)x1[2]; af[7] = (__bf16)x1[3];
                #pragma unroll
                for (int nf = 0; nf < 4; ++nf)
                    acc[mf][nf] = __builtin_amdgcn_mfma_f32_16x16x32_bf16(af, Bf[nf][s], acc[mf][nf], 0, 0, 0);
            }
        }

        // epilogue: C row = q*4+jj (pixel), col = l15 (f)
        #pragma unroll
        for (int mf = 0; mf < 2; ++mf) {
            #pragma unroll
            for (int jj = 0; jj < 4; ++jj) {
                const int P  = wv * 32 + mf * 16 + q * 4 + jj;
                const int hh = th * 16 + (P >> 3);
                const int ww = tw * 8 + (P & 7);
                float* op = out + ((size_t)b * 16384 + hh * 128 + ww) * 64 + l15;
                #pragma unroll
                for (int nf = 0; nf < 4; ++nf)
                    op[nf * 16] = acc[mf][nf][jj] + bagg_v[nf];
            }
        }
        __syncthreads();                             // drains next-tile DMA + flips buffers
    }
}

extern "C" void kernel_launch(void* const* d_in, const int* in_sizes, int n_in,
                              void* d_out, int out_size, void* d_ws, size_t ws_size,
                              hipStream_t stream) {
    const float* x   = (const float*)d_in[0];
    const float* Wk  = (const float*)d_in[1];
    const float* bk  = (const float*)d_in[2];
    const float* w1  = (const float*)d_in[3];
    const float* b1  = (const float*)d_in[4];
    const float* w2  = (const float*)d_in[5];
    const float* b2  = (const float*)d_in[6];
    float* out = (float*)d_out;

    char* ws = (char*)d_ws;
    float* pooled = (float*)ws;                         // 8 KB
    float* bagg   = (float*)(ws + 8192);                // 8 KB
    float* zeros  = (float*)(ws + 16384);               // 4 KB
    __hip_bfloat16* Wt = (__hip_bfloat16*)(ws + 20480); // 2.25 MB

    hipMemsetAsync(pooled, 0, 8192, stream);
    hipMemsetAsync(zeros, 0, 4096, stream);
    pool_kernel<<<2048, 256, 0, stream>>>(x, pooled);
    wagg_kernel<<<dim3(32, 9), 256, 0, stream>>>(pooled, Wk, bk, w1, b1, w2, b2, Wt, bagg);

    static bool attr_set = false;
    if (!attr_set) {
        hipFuncSetAttribute((const void*)conv_kernel,
                            hipFuncAttributeMaxDynamicSharedMemorySize, 2 * XS_BYTES);
        attr_set = true;
    }
    conv_kernel<<<256, 256, 2 * XS_BYTES, stream>>>(x, Wt, bagg, zeros, out);
}